// Round 10
// baseline (440.297 us; speedup 1.0000x reference)
//
#include <hip/hip_runtime.h>
#include <math.h>

// Problem constants
#define HDIM 128
#define WDIM 256
#define NPIX (HDIM*WDIM)   // 32768
#define LD 64
#define S 16
#define J 25
#define KS 21
#define NH 8
#define HMLP 32
#define FFN_H 256
#define PSI_ROW (J*KS)     // 525
#define WP_ROW (J*S)       // 400

__device__ __forceinline__ float gelu_exact(float v) {
    return 0.5f * v * (1.0f + erff(v * 0.70710678118654752440f));
}

// tanh-approx gelu (max |err| vs exact ~3e-3; threshold budget is 0.129)
__device__ __forceinline__ float gelu_fast(float x) {
    float x2 = x * x;
    float a  = __builtin_fmaf(x2, 0.035677408136f, 0.7978845608028654f);
    float z  = a * x * 2.885390081777927f;          // 2*log2(e)*u
    z = fmaxf(-30.f, fminf(30.f, z));               // saturate tanh safely
    float e  = __builtin_exp2f(z);
    float th = (e - 1.f) * __builtin_amdgcn_rcpf(e + 1.f);  // d>=1, safe
    float s  = 0.5f * x;
    return __builtin_fmaf(s, th, s);
}

// ---------------------------------------------------------------------------
// Kernel 1: per-row modulation gamma/beta.  gb[h*32 + j] = m[h][j]
// ---------------------------------------------------------------------------
__global__ __launch_bounds__(128) void k_mod(
    const float* __restrict__ x, const float* __restrict__ lm_w1,
    const float* __restrict__ lm_b1, const float* __restrict__ lm_w2,
    const float* __restrict__ lm_b2, float* __restrict__ gb)
{
    int h = threadIdx.x;              // 0..127
    float s0 = x[h * WDIM * 66 + 64]; // sin_cos at w=0
    float s1 = x[h * WDIM * 66 + 65];
    float t[32];
#pragma unroll
    for (int j = 0; j < 32; ++j)
        t[j] = gelu_exact(s0 * lm_w1[j] + s1 * lm_w1[32 + j] + lm_b1[j]);
#pragma unroll
    for (int j = 0; j < 32; ++j) {
        float m = lm_b2[j];
#pragma unroll
        for (int cc = 0; cc < 32; ++cc) m += t[cc] * lm_w2[cc * 32 + j];
        gb[h * 32 + j] = m;
    }
}

// ---------------------------------------------------------------------------
// Kernel 2: Wp[p][j][o] = sum_k psi[p][j][k] * disco_w[o][k]
// ---------------------------------------------------------------------------
__global__ __launch_bounds__(256) void k_wp(
    const float* __restrict__ psi, const float* __restrict__ disco_w,
    float* __restrict__ wp)
{
    __shared__ alignas(16) float psi_s[4][J * 24];   // stride 24 (pad from 21)
    __shared__ alignas(16) float dw_s[16 * 28];      // stride 28 (pad from 21)

    const int tid = threadIdx.x;
    const int wid = tid >> 6;
    const int lane = tid & 63;

    for (int i = tid; i < 16 * KS; i += 256) dw_s[(i / KS) * 28 + (i % KS)] = disco_w[i];
    __syncthreads();

    const int p = blockIdx.x * 4 + wid;
    const float* pr = psi + (size_t)p * PSI_ROW;
#pragma unroll
    for (int t = 0; t < 9; ++t) {
        int idx = t * 64 + lane;
        if (idx < PSI_ROW) {
            int j = idx / KS, k = idx - j * KS;
            psi_s[wid][j * 24 + k] = pr[idx];
        }
    }
    asm volatile("s_waitcnt lgkmcnt(0) vmcnt(0)" ::: "memory");

#pragma unroll
    for (int i = 0; i < 7; ++i) {
        int e = i * 64 + lane;
        if (e < WP_ROW) {
            int j = e >> 4, o = e & 15;
            const float* pj = &psi_s[wid][j * 24];
            const float* wo = &dw_s[o * 28];
            float acc = pj[20] * wo[20];
#pragma unroll
            for (int t = 0; t < 5; ++t) {
                float4 a = *(const float4*)(pj + t * 4);
                float4 b = *(const float4*)(wo + t * 4);
                acc += a.x * b.x + a.y * b.y + a.z * b.z + a.w * b.w;
            }
            wp[(size_t)p * WP_ROW + e] = acc;
        }
    }
}

// ---------------------------------------------------------------------------
// head MLP: 16 -> 32 (gelu) -> 1, hidden computed in 4 chunks of 8
// ---------------------------------------------------------------------------
__device__ __forceinline__ float head_mlp(
    const float y[16], int n, const float* __restrict__ hw1_s,
    const float* __restrict__ hb1_s, const float* __restrict__ hw2_s)
{
    float ho = 0.f;
#pragma unroll
    for (int c8 = 0; c8 < 4; ++c8) {
        float t8[8];
        {
            const float4* hb = (const float4*)&hb1_s[n * 36 + c8 * 8];
            float4 b0 = hb[0], b1 = hb[1];
            t8[0] = b0.x; t8[1] = b0.y; t8[2] = b0.z; t8[3] = b0.w;
            t8[4] = b1.x; t8[5] = b1.y; t8[6] = b1.z; t8[7] = b1.w;
        }
#pragma unroll
        for (int s = 0; s < 16; ++s) {
            float ys = y[s];
            const float* hr = &hw1_s[n * 516 + s * 32 + c8 * 8];
            float4 h0 = *(const float4*)(hr);
            float4 h1 = *(const float4*)(hr + 4);
            t8[0] += ys * h0.x; t8[1] += ys * h0.y;
            t8[2] += ys * h0.z; t8[3] += ys * h0.w;
            t8[4] += ys * h1.x; t8[5] += ys * h1.y;
            t8[6] += ys * h1.z; t8[7] += ys * h1.w;
        }
#pragma unroll
        for (int j = 0; j < 8; ++j)
            ho += gelu_fast(t8[j]) * hw2_s[n * 33 + c8 * 8 + j];
    }
    return ho;
}

// ---------------------------------------------------------------------------
// Kernel 3: disco apply + gamma/beta + head MLP + residual -> x2[p*64+c]
// 256 threads = 4 waves; 8 pixels per wave (same row). Loop-invariant
// gamma/beta/disco_b/h_b2 hoisted into registers (grid-limited occupancy
// means the extra ~50 VGPRs are free).
// ---------------------------------------------------------------------------
__global__ __launch_bounds__(256) void k_disco(
    const float* __restrict__ x, const float* __restrict__ wp,
    const float* __restrict__ disco_b, const float* __restrict__ gb,
    const float* __restrict__ h_w1, const float* __restrict__ h_b1,
    const float* __restrict__ h_w2, const float* __restrict__ h_b2,
    float* __restrict__ x2out)
{
    __shared__ alignas(16) float4 wp_s[4][J * 4];     // [wid][j*4+o4]
    __shared__ alignas(16) float hw1_s[8 * 516];      // n*516 + s*32 + c2
    __shared__ alignas(16) float hb1_s[8 * 36];
    __shared__ float hw2_s[8 * 33];
    __shared__ float hb2_s[8];

    const int tid = threadIdx.x;
    const int wid = tid >> 6;
    const int lane = tid & 63;

    for (int i = tid; i < NH * S * HMLP; i += 256) {
        int n = i >> 9;
        hw1_s[n * 516 + (i & 511)] = h_w1[i];
    }
    { int i = tid; hw2_s[(i >> 5) * 33 + (i & 31)] = h_w2[i]; }
    { int i = tid; hb1_s[(i >> 5) * 36 + (i & 31)] = h_b1[i]; }
    if (tid < 8)  hb2_s[tid] = h_b2[tid];
    __syncthreads();

    const int pbase = (blockIdx.x * 4 + wid) * 8;   // 8 pixels, same row
    const int h = pbase >> 8;
    const int w0 = pbase & 255;
    const int c = lane;
    const int n = lane >> 3;

    int rowoff[5];
#pragma unroll
    for (int a = 0; a < 5; ++a) {
        int hh = h + a - 2;
        hh = hh < 0 ? 0 : (hh > HDIM - 1 ? HDIM - 1 : hh);
        rowoff[a] = hh << 8;
    }

    // hoist loop invariants into registers
    float gbr[16], ber[16], dbr[16];
    {
        const float* gbp = gb + h * 32;
#pragma unroll
        for (int o4 = 0; o4 < 4; ++o4) {
            float4 g  = *(const float4*)(gbp + o4 * 4);
            float4 be = *(const float4*)(gbp + 16 + o4 * 4);
            float4 d  = *(const float4*)(disco_b + o4 * 4);
            gbr[o4*4+0] = g.x;  gbr[o4*4+1] = g.y;  gbr[o4*4+2] = g.z;  gbr[o4*4+3] = g.w;
            ber[o4*4+0] = be.x; ber[o4*4+1] = be.y; ber[o4*4+2] = be.z; ber[o4*4+3] = be.w;
            dbr[o4*4+0] = d.x;  dbr[o4*4+1] = d.y;  dbr[o4*4+2] = d.z;  dbr[o4*4+3] = d.w;
        }
    }
    const float hb2r = hb2_s[n];

    for (int it = 0; it < 8; ++it) {
        const int p = pbase + it;
        const int w = w0 + it;

        // stage this pixel's Wp into our wave's LDS region
        const float4* wpg = (const float4*)(wp + (size_t)p * WP_ROW);
#pragma unroll
        for (int t = 0; t < 2; ++t) {
            int idx = t * 64 + lane;
            if (idx < J * 4) wp_s[wid][idx] = wpg[idx];
        }
        asm volatile("s_waitcnt lgkmcnt(0) vmcnt(0)" ::: "memory");

        float y[16];
#pragma unroll
        for (int o = 0; o < 16; ++o) y[o] = dbr[o];

        float xc = 0.f;
#pragma unroll
        for (int a = 0; a < 5; ++a) {
#pragma unroll
            for (int b = 0; b < 5; ++b) {
                int ww = (w + b - 2) & 255;
                float xv = x[(size_t)(rowoff[a] + ww) * 66 + c];
                if (a == 2 && b == 2) xc = xv;
                const float4* wrow = &wp_s[wid][(a * 5 + b) * 4];
#pragma unroll
                for (int o4 = 0; o4 < 4; ++o4) {
                    float4 wv = wrow[o4];
                    y[o4 * 4 + 0] += xv * wv.x;
                    y[o4 * 4 + 1] += xv * wv.y;
                    y[o4 * 4 + 2] += xv * wv.z;
                    y[o4 * 4 + 3] += xv * wv.w;
                }
            }
        }

#pragma unroll
        for (int o = 0; o < 16; ++o)
            y[o] = y[o] * gbr[o] + ber[o];

        float ho = head_mlp(y, n, hw1_s, hb1_s, hw2_s);

        x2out[(size_t)p * 64 + c] = ho + hb2r + xc;
    }
}

// ---------------------------------------------------------------------------
// Kernel 4a: FFN stage 1 (f_w1 rows 64,65 are zero -> K=64).
// 256 threads = 4 waves; wave w owns output-channel chunk n = w*64+lane,
// with its 64 weights held in REGISTERS. Per pixel: 1 coalesced x2-row load
// -> wave-private LDS row buffer -> 16 broadcast ds_read_b128 + 64 FMA.
// Output transposed through a [64][65] LDS tile -> coalesced f1t[n][p].
// No barriers (all LDS traffic is wave-private).
// ---------------------------------------------------------------------------
__global__ __launch_bounds__(256) void k_ffn1(
    const float* __restrict__ x2, const float* __restrict__ f_w1,
    const float* __restrict__ f_b1, float* __restrict__ f1t)
{
    __shared__ alignas(16) float rowbuf[4][64];
    __shared__ float ttile[4][64][65];

    const int tid = threadIdx.x;
    const int w   = tid >> 6;      // wave = n-chunk
    const int ln  = tid & 63;
    const int p0  = blockIdx.x * 64;

    // per-lane weights: f_w1[k][w*64+ln], k=0..63
    float wreg[64];
#pragma unroll
    for (int k = 0; k < 64; ++k)
        wreg[k] = f_w1[k * FFN_H + w * 64 + ln];
    const float bias = f_b1[w * 64 + ln];

    for (int px = 0; px < 64; ++px) {
        const int p = p0 + px;
        rowbuf[w][ln] = x2[(size_t)p * 64 + ln];
        asm volatile("s_waitcnt lgkmcnt(0) vmcnt(0)" ::: "memory");

        float acc = bias;
#pragma unroll
        for (int k4 = 0; k4 < 16; ++k4) {
            float4 xv = *(const float4*)&rowbuf[w][k4 * 4];
            acc += xv.x * wreg[k4 * 4 + 0] + xv.y * wreg[k4 * 4 + 1]
                 + xv.z * wreg[k4 * 4 + 2] + xv.w * wreg[k4 * 4 + 3];
        }
        ttile[w][px][ln] = gelu_fast(acc);
    }
    asm volatile("s_waitcnt lgkmcnt(0)" ::: "memory");

    // transpose out: f1t[(w*64+r)][p0+ln]
    for (int r = 0; r < 64; ++r)
        f1t[(size_t)(w * 64 + r) * NPIX + p0 + ln] = ttile[w][ln][r];
}

// ---------------------------------------------------------------------------
// Kernel 4b: FFN stage 2 + residual + output assembly.
// 256 threads = 4 waves x 64 pixels; f_w2 half staged once in LDS (32 KB),
// read via uniform broadcast. f1t reads coalesced.
// ---------------------------------------------------------------------------
__global__ __launch_bounds__(256) void k_ffn2(
    const float* __restrict__ x, const float* __restrict__ x2,
    const float* __restrict__ f1t, const float* __restrict__ f_w2,
    const float* __restrict__ f_b2, float* __restrict__ out)
{
    __shared__ alignas(16) float w2s[256 * 32];

    const int tid = threadIdx.x;
    const int wv  = tid >> 6;
    const int ln  = tid & 63;
    const int half  = blockIdx.x & 1;
    const int cbase = half * 32;
    const int p0    = (blockIdx.x >> 1) * 256;

    for (int i = tid; i < 256 * 32; i += 256)
        w2s[i] = f_w2[(i >> 5) * 64 + cbase + (i & 31)];
    __syncthreads();

    const int p = p0 + wv * 64 + ln;

    float acc[32];
#pragma unroll
    for (int c4 = 0; c4 < 8; ++c4) {
        float4 bv = *(const float4*)(f_b2 + cbase + c4 * 4);
        acc[c4 * 4 + 0] = bv.x; acc[c4 * 4 + 1] = bv.y;
        acc[c4 * 4 + 2] = bv.z; acc[c4 * 4 + 3] = bv.w;
    }

    for (int q = 0; q < FFN_H; ++q) {
        float f1v = f1t[(size_t)q * NPIX + p];
        const float4* wr = (const float4*)&w2s[q * 32];
#pragma unroll
        for (int c4 = 0; c4 < 8; ++c4) {
            float4 wv = wr[c4];
            acc[c4 * 4 + 0] += f1v * wv.x;
            acc[c4 * 4 + 1] += f1v * wv.y;
            acc[c4 * 4 + 2] += f1v * wv.z;
            acc[c4 * 4 + 3] += f1v * wv.w;
        }
    }

    const float4* x2p = (const float4*)(x2 + (size_t)p * 64 + cbase);
#pragma unroll
    for (int c4 = 0; c4 < 8; ++c4) {
        float4 xv = x2p[c4];
        out[(size_t)p * 66 + cbase + c4 * 4 + 0] = acc[c4 * 4 + 0] + xv.x;
        out[(size_t)p * 66 + cbase + c4 * 4 + 1] = acc[c4 * 4 + 1] + xv.y;
        out[(size_t)p * 66 + cbase + c4 * 4 + 2] = acc[c4 * 4 + 2] + xv.z;
        out[(size_t)p * 66 + cbase + c4 * 4 + 3] = acc[c4 * 4 + 3] + xv.w;
    }
    if (half) {
        out[(size_t)p * 66 + 64] = x[(size_t)p * 66 + 64];
        out[(size_t)p * 66 + 65] = x[(size_t)p * 66 + 65];
    }
}

// ---------------------------------------------------------------------------
extern "C" void kernel_launch(void* const* d_in, const int* in_sizes, int n_in,
                              void* d_out, int out_size, void* d_ws, size_t ws_size,
                              hipStream_t stream) {
    const float* x       = (const float*)d_in[0];
    const float* psi     = (const float*)d_in[2];
    const float* disco_w = (const float*)d_in[3];
    const float* disco_b = (const float*)d_in[4];
    const float* lm_w1   = (const float*)d_in[5];
    const float* lm_b1   = (const float*)d_in[6];
    const float* lm_w2   = (const float*)d_in[7];
    const float* lm_b2   = (const float*)d_in[8];
    const float* h_w1    = (const float*)d_in[9];
    const float* h_b1    = (const float*)d_in[10];
    const float* h_w2    = (const float*)d_in[11];
    const float* h_b2    = (const float*)d_in[12];
    const float* f_w1    = (const float*)d_in[13];
    const float* f_b1    = (const float*)d_in[14];
    const float* f_w2    = (const float*)d_in[15];
    const float* f_b2    = (const float*)d_in[16];
    float* out = (float*)d_out;

    // workspace layout (floats): gb[4096] | x2[NPIX*64] | union{ wp[NPIX*400], f1t[256*NPIX] }
    float* gb  = (float*)d_ws;
    float* x2  = gb + 4096;
    float* wp  = x2 + (size_t)NPIX * 64;
    float* f1t = wp;                       // f1t aliases wp (wp dead after k_disco)

    k_mod  <<<1,    128, 0, stream>>>(x, lm_w1, lm_b1, lm_w2, lm_b2, gb);
    k_wp   <<<8192, 256, 0, stream>>>(psi, disco_w, wp);
    k_disco<<<1024, 256, 0, stream>>>(x, wp, disco_b, gb,
                                      h_w1, h_b1, h_w2, h_b2, x2);
    k_ffn1 <<<512,  256, 0, stream>>>(x2, f_w1, f_b1, f1t);
    k_ffn2 <<<256,  256, 0, stream>>>(x, x2, f1t, f_w2, f_b2, out);
}

// Round 12
// 362.722 us; speedup vs baseline: 1.2139x; 1.2139x over previous
//
#include <hip/hip_runtime.h>
#include <math.h>

// Problem constants
#define HDIM 128
#define WDIM 256
#define NPIX (HDIM*WDIM)   // 32768
#define LD 64
#define S 16
#define J 25
#define KS 21
#define NH 8
#define HMLP 32
#define FFN_H 256
#define PSI_ROW (J*KS)     // 525
#define WP_ROW (J*S)       // 400

__device__ __forceinline__ float gelu_exact(float v) {
    return 0.5f * v * (1.0f + erff(v * 0.70710678118654752440f));
}

// tanh-approx gelu (max |err| vs exact ~3e-3; threshold budget is 0.129)
__device__ __forceinline__ float gelu_fast(float x) {
    float x2 = x * x;
    float a  = __builtin_fmaf(x2, 0.035677408136f, 0.7978845608028654f);
    float z  = a * x * 2.885390081777927f;          // 2*log2(e)*u
    z = fmaxf(-30.f, fminf(30.f, z));               // saturate tanh safely
    float e  = __builtin_exp2f(z);
    float th = (e - 1.f) * __builtin_amdgcn_rcpf(e + 1.f);  // d>=1, safe
    float s  = 0.5f * x;
    return __builtin_fmaf(s, th, s);
}

// ---------------------------------------------------------------------------
// Kernel 1: per-row modulation gamma/beta.  gb[h*32 + j] = m[h][j]
// ---------------------------------------------------------------------------
__global__ __launch_bounds__(128) void k_mod(
    const float* __restrict__ x, const float* __restrict__ lm_w1,
    const float* __restrict__ lm_b1, const float* __restrict__ lm_w2,
    const float* __restrict__ lm_b2, float* __restrict__ gb)
{
    int h = threadIdx.x;              // 0..127
    float s0 = x[h * WDIM * 66 + 64]; // sin_cos at w=0
    float s1 = x[h * WDIM * 66 + 65];
    float t[32];
#pragma unroll
    for (int j = 0; j < 32; ++j)
        t[j] = gelu_exact(s0 * lm_w1[j] + s1 * lm_w1[32 + j] + lm_b1[j]);
#pragma unroll
    for (int j = 0; j < 32; ++j) {
        float m = lm_b2[j];
#pragma unroll
        for (int cc = 0; cc < 32; ++cc) m += t[cc] * lm_w2[cc * 32 + j];
        gb[h * 32 + j] = m;
    }
}

// ---------------------------------------------------------------------------
// Kernel 2: Wp[p][j][o] = sum_k psi[p][j][k] * disco_w[o][k]
// Lane's o = lane&15 is loop-invariant -> dw[o] hoisted into 21 REGISTERS.
// Lane covers j = (lane>>4) + 4*i. Per output: 6 LDS reads (was ~10).
// ---------------------------------------------------------------------------
__global__ __launch_bounds__(256) void k_wp(
    const float* __restrict__ psi, const float* __restrict__ disco_w,
    float* __restrict__ wp)
{
    __shared__ alignas(16) float psi_s[4][J * 24];   // stride 24 (pad from 21)
    __shared__ alignas(16) float dw_s[16 * 28];      // stride 28 (pad from 21)

    const int tid = threadIdx.x;
    const int wid = tid >> 6;
    const int lane = tid & 63;

    for (int i = tid; i < 16 * KS; i += 256) dw_s[(i / KS) * 28 + (i % KS)] = disco_w[i];
    __syncthreads();

    // hoist this lane's dw row into registers
    const int o  = lane & 15;
    const int jg = lane >> 4;
    float dwr[21];
    {
        const float* wo = &dw_s[o * 28];
#pragma unroll
        for (int t = 0; t < 5; ++t) {
            float4 v = *(const float4*)(wo + t * 4);
            dwr[t * 4 + 0] = v.x; dwr[t * 4 + 1] = v.y;
            dwr[t * 4 + 2] = v.z; dwr[t * 4 + 3] = v.w;
        }
        dwr[20] = wo[20];
    }

    const int p = blockIdx.x * 4 + wid;
    const float* pr = psi + (size_t)p * PSI_ROW;
#pragma unroll
    for (int t = 0; t < 9; ++t) {
        int idx = t * 64 + lane;
        if (idx < PSI_ROW) {
            int j = idx / KS, k = idx - j * KS;
            psi_s[wid][j * 24 + k] = pr[idx];
        }
    }
    asm volatile("s_waitcnt lgkmcnt(0) vmcnt(0)" ::: "memory");

#pragma unroll
    for (int i = 0; i < 7; ++i) {
        int j = jg + 4 * i;
        if (j < J) {
            const float* pj = &psi_s[wid][j * 24];
            float acc = pj[20] * dwr[20];
#pragma unroll
            for (int t = 0; t < 5; ++t) {
                float4 a = *(const float4*)(pj + t * 4);
                acc += a.x * dwr[t * 4 + 0] + a.y * dwr[t * 4 + 1]
                     + a.z * dwr[t * 4 + 2] + a.w * dwr[t * 4 + 3];
            }
            wp[(size_t)p * WP_ROW + j * 16 + o] = acc;
        }
    }
}

// ---------------------------------------------------------------------------
// head MLP: 16 -> 32 (gelu) -> 1, hidden computed in 4 chunks of 8
// ---------------------------------------------------------------------------
__device__ __forceinline__ float head_mlp(
    const float y[16], int n, const float* __restrict__ hw1_s,
    const float* __restrict__ hb1_s, const float* __restrict__ hw2_s)
{
    float ho = 0.f;
#pragma unroll
    for (int c8 = 0; c8 < 4; ++c8) {
        float t8[8];
        {
            const float4* hb = (const float4*)&hb1_s[n * 36 + c8 * 8];
            float4 b0 = hb[0], b1 = hb[1];
            t8[0] = b0.x; t8[1] = b0.y; t8[2] = b0.z; t8[3] = b0.w;
            t8[4] = b1.x; t8[5] = b1.y; t8[6] = b1.z; t8[7] = b1.w;
        }
#pragma unroll
        for (int s = 0; s < 16; ++s) {
            float ys = y[s];
            const float* hr = &hw1_s[n * 516 + s * 32 + c8 * 8];
            float4 h0 = *(const float4*)(hr);
            float4 h1 = *(const float4*)(hr + 4);
            t8[0] += ys * h0.x; t8[1] += ys * h0.y;
            t8[2] += ys * h0.z; t8[3] += ys * h0.w;
            t8[4] += ys * h1.x; t8[5] += ys * h1.y;
            t8[6] += ys * h1.z; t8[7] += ys * h1.w;
        }
#pragma unroll
        for (int j = 0; j < 8; ++j)
            ho += gelu_fast(t8[j]) * hw2_s[n * 33 + c8 * 8 + j];
    }
    return ho;
}

// ---------------------------------------------------------------------------
// Kernel 3: disco apply + gamma/beta + head MLP + residual -> x2[p*64+c]
// EXACT R7 body (VGPR 60, VALUBusy 74% proven) with ONE knob changed:
// 4 pixels per wave (was 8), grid 2048 (was 1024) -> 8 waves/SIMD.
// ---------------------------------------------------------------------------
__global__ __launch_bounds__(256) void k_disco(
    const float* __restrict__ x, const float* __restrict__ wp,
    const float* __restrict__ disco_b, const float* __restrict__ gb,
    const float* __restrict__ h_w1, const float* __restrict__ h_b1,
    const float* __restrict__ h_w2, const float* __restrict__ h_b2,
    float* __restrict__ x2out)
{
    __shared__ alignas(16) float4 wp_s[4][J * 4];     // [wid][j*4+o4]
    __shared__ alignas(16) float hw1_s[8 * 516];      // n*516 + s*32 + c2
    __shared__ alignas(16) float hb1_s[8 * 36];
    __shared__ float hw2_s[8 * 33];
    __shared__ alignas(16) float db_s[16];
    __shared__ float hb2_s[8];

    const int tid = threadIdx.x;
    const int wid = tid >> 6;
    const int lane = tid & 63;

    for (int i = tid; i < NH * S * HMLP; i += 256) {
        int n = i >> 9;
        hw1_s[n * 516 + (i & 511)] = h_w1[i];
    }
    { int i = tid; hw2_s[(i >> 5) * 33 + (i & 31)] = h_w2[i]; }
    { int i = tid; hb1_s[(i >> 5) * 36 + (i & 31)] = h_b1[i]; }
    if (tid < 16) db_s[tid] = disco_b[tid];
    if (tid < 8)  hb2_s[tid] = h_b2[tid];
    __syncthreads();

    const int pbase = (blockIdx.x * 4 + wid) * 4;   // 4 pixels, same row
    const int h = pbase >> 8;
    const int w0 = pbase & 255;
    const int c = lane;
    const int n = lane >> 3;

    int rowoff[5];
#pragma unroll
    for (int a = 0; a < 5; ++a) {
        int hh = h + a - 2;
        hh = hh < 0 ? 0 : (hh > HDIM - 1 ? HDIM - 1 : hh);
        rowoff[a] = hh << 8;
    }
    const float* gbp = gb + h * 32;

    for (int it = 0; it < 4; ++it) {
        const int p = pbase + it;
        const int w = w0 + it;

        // stage this pixel's Wp into our wave's LDS region
        const float4* wpg = (const float4*)(wp + (size_t)p * WP_ROW);
#pragma unroll
        for (int t = 0; t < 2; ++t) {
            int idx = t * 64 + lane;
            if (idx < J * 4) wp_s[wid][idx] = wpg[idx];
        }
        asm volatile("s_waitcnt lgkmcnt(0) vmcnt(0)" ::: "memory");

        // y init from disco_b (uniform LDS broadcast)
        float y[16];
#pragma unroll
        for (int o4 = 0; o4 < 4; ++o4) {
            float4 d = ((const float4*)db_s)[o4];
            y[o4 * 4 + 0] = d.x; y[o4 * 4 + 1] = d.y;
            y[o4 * 4 + 2] = d.z; y[o4 * 4 + 3] = d.w;
        }

        // fused gather + y update
        float xc = 0.f;
#pragma unroll
        for (int a = 0; a < 5; ++a) {
#pragma unroll
            for (int b = 0; b < 5; ++b) {
                int ww = (w + b - 2) & 255;
                float xv = x[(size_t)(rowoff[a] + ww) * 66 + c];
                if (a == 2 && b == 2) xc = xv;
                const float4* wrow = &wp_s[wid][(a * 5 + b) * 4];
#pragma unroll
                for (int o4 = 0; o4 < 4; ++o4) {
                    float4 wv = wrow[o4];
                    y[o4 * 4 + 0] += xv * wv.x;
                    y[o4 * 4 + 1] += xv * wv.y;
                    y[o4 * 4 + 2] += xv * wv.z;
                    y[o4 * 4 + 3] += xv * wv.w;
                }
            }
        }

        // gamma/beta (uniform per row, L1-hot)
#pragma unroll
        for (int o = 0; o < 16; ++o)
            y[o] = y[o] * gbp[o] + gbp[16 + o];

        float ho = head_mlp(y, n, hw1_s, hb1_s, hw2_s);

        x2out[(size_t)p * 64 + c] = ho + hb2_s[n] + xc;
    }
}

// ---------------------------------------------------------------------------
// Kernel 4a: FFN stage 1 (f_w1 rows 64,65 are zero -> K=64).
// 256 threads = 4 waves; wave w owns output-channel chunk n = w*64+lane,
// weights in registers. Software-pipelined: pixel px+1's row load issues
// before px's compute, hiding global latency under the 16 LDS reads + FMAs.
// ---------------------------------------------------------------------------
__global__ __launch_bounds__(256) void k_ffn1(
    const float* __restrict__ x2, const float* __restrict__ f_w1,
    const float* __restrict__ f_b1, float* __restrict__ f1t)
{
    __shared__ alignas(16) float rowbuf[4][64];
    __shared__ float ttile[4][64][65];

    const int tid = threadIdx.x;
    const int w   = tid >> 6;      // wave = n-chunk
    const int ln  = tid & 63;
    const int p0  = blockIdx.x * 64;

    // per-lane weights: f_w1[k][w*64+ln], k=0..63
    float wreg[64];
#pragma unroll
    for (int k = 0; k < 64; ++k)
        wreg[k] = f_w1[k * FFN_H + w * 64 + ln];
    const float bias = f_b1[w * 64 + ln];

    float cur = x2[(size_t)p0 * 64 + ln];
    for (int px = 0; px < 64; ++px) {
        float nxtv = 0.f;
        if (px < 63) nxtv = x2[(size_t)(p0 + px + 1) * 64 + ln];  // prefetch

        rowbuf[w][ln] = cur;
        asm volatile("s_waitcnt lgkmcnt(0)" ::: "memory");

        float acc = bias;
#pragma unroll
        for (int k4 = 0; k4 < 16; ++k4) {
            float4 xv = *(const float4*)&rowbuf[w][k4 * 4];
            acc += xv.x * wreg[k4 * 4 + 0] + xv.y * wreg[k4 * 4 + 1]
                 + xv.z * wreg[k4 * 4 + 2] + xv.w * wreg[k4 * 4 + 3];
        }
        ttile[w][px][ln] = gelu_fast(acc);
        cur = nxtv;
    }
    asm volatile("s_waitcnt lgkmcnt(0)" ::: "memory");

    // transpose out: f1t[(w*64+r)][p0+ln]
    for (int r = 0; r < 64; ++r)
        f1t[(size_t)(w * 64 + r) * NPIX + p0 + ln] = ttile[w][ln][r];
}

// ---------------------------------------------------------------------------
// Kernel 4b: FFN stage 2 + residual + output assembly.
// 256 threads = 4 waves x 64 pixels; f_w2 half staged once in LDS (32 KB),
// read via uniform broadcast. f1t reads coalesced.
// ---------------------------------------------------------------------------
__global__ __launch_bounds__(256) void k_ffn2(
    const float* __restrict__ x, const float* __restrict__ x2,
    const float* __restrict__ f1t, const float* __restrict__ f_w2,
    const float* __restrict__ f_b2, float* __restrict__ out)
{
    __shared__ alignas(16) float w2s[256 * 32];

    const int tid = threadIdx.x;
    const int wv  = tid >> 6;
    const int ln  = tid & 63;
    const int half  = blockIdx.x & 1;
    const int cbase = half * 32;
    const int p0    = (blockIdx.x >> 1) * 256;

    for (int i = tid; i < 256 * 32; i += 256)
        w2s[i] = f_w2[(i >> 5) * 64 + cbase + (i & 31)];
    __syncthreads();

    const int p = p0 + wv * 64 + ln;

    float acc[32];
#pragma unroll
    for (int c4 = 0; c4 < 8; ++c4) {
        float4 bv = *(const float4*)(f_b2 + cbase + c4 * 4);
        acc[c4 * 4 + 0] = bv.x; acc[c4 * 4 + 1] = bv.y;
        acc[c4 * 4 + 2] = bv.z; acc[c4 * 4 + 3] = bv.w;
    }

    for (int q = 0; q < FFN_H; ++q) {
        float f1v = f1t[(size_t)q * NPIX + p];
        const float4* wr = (const float4*)&w2s[q * 32];
#pragma unroll
        for (int c4 = 0; c4 < 8; ++c4) {
            float4 wv = wr[c4];
            acc[c4 * 4 + 0] += f1v * wv.x;
            acc[c4 * 4 + 1] += f1v * wv.y;
            acc[c4 * 4 + 2] += f1v * wv.z;
            acc[c4 * 4 + 3] += f1v * wv.w;
        }
    }

    const float4* x2p = (const float4*)(x2 + (size_t)p * 64 + cbase);
#pragma unroll
    for (int c4 = 0; c4 < 8; ++c4) {
        float4 xv = x2p[c4];
        out[(size_t)p * 66 + cbase + c4 * 4 + 0] = acc[c4 * 4 + 0] + xv.x;
        out[(size_t)p * 66 + cbase + c4 * 4 + 1] = acc[c4 * 4 + 1] + xv.y;
        out[(size_t)p * 66 + cbase + c4 * 4 + 2] = acc[c4 * 4 + 2] + xv.z;
        out[(size_t)p * 66 + cbase + c4 * 4 + 3] = acc[c4 * 4 + 3] + xv.w;
    }
    if (half) {
        out[(size_t)p * 66 + 64] = x[(size_t)p * 66 + 64];
        out[(size_t)p * 66 + 65] = x[(size_t)p * 66 + 65];
    }
}

// ---------------------------------------------------------------------------
extern "C" void kernel_launch(void* const* d_in, const int* in_sizes, int n_in,
                              void* d_out, int out_size, void* d_ws, size_t ws_size,
                              hipStream_t stream) {
    const float* x       = (const float*)d_in[0];
    const float* psi     = (const float*)d_in[2];
    const float* disco_w = (const float*)d_in[3];
    const float* disco_b = (const float*)d_in[4];
    const float* lm_w1   = (const float*)d_in[5];
    const float* lm_b1   = (const float*)d_in[6];
    const float* lm_w2   = (const float*)d_in[7];
    const float* lm_b2   = (const float*)d_in[8];
    const float* h_w1    = (const float*)d_in[9];
    const float* h_b1    = (const float*)d_in[10];
    const float* h_w2    = (const float*)d_in[11];
    const float* h_b2    = (const float*)d_in[12];
    const float* f_w1    = (const float*)d_in[13];
    const float* f_b1    = (const float*)d_in[14];
    const float* f_w2    = (const float*)d_in[15];
    const float* f_b2    = (const float*)d_in[16];
    float* out = (float*)d_out;

    // workspace layout (floats): gb[4096] | x2[NPIX*64] | union{ wp[NPIX*400], f1t[256*NPIX] }
    float* gb  = (float*)d_ws;
    float* x2  = gb + 4096;
    float* wp  = x2 + (size_t)NPIX * 64;
    float* f1t = wp;                       // f1t aliases wp (wp dead after k_disco)

    k_mod  <<<1,    128, 0, stream>>>(x, lm_w1, lm_b1, lm_w2, lm_b2, gb);
    k_wp   <<<8192, 256, 0, stream>>>(psi, disco_w, wp);
    k_disco<<<2048, 256, 0, stream>>>(x, wp, disco_b, gb,
                                      h_w1, h_b1, h_w2, h_b2, x2);
    k_ffn1 <<<512,  256, 0, stream>>>(x2, f_w1, f_b1, f1t);
    k_ffn2 <<<256,  256, 0, stream>>>(x, x2, f1t, f_w2, f_b2, out);
}